// Round 3
// baseline (204.289 us; speedup 1.0000x reference)
//
#include <hip/hip_runtime.h>
#include <math.h>

#define BB 32
#define CC 128
#define OO 256
#define HWSZ 3136
#define HW4 (HWSZ*4)
#define BN_EPS 1e-5f
#define DW_THR 4.0f

typedef __attribute__((ext_vector_type(8))) short short8;
typedef __attribute__((ext_vector_type(4))) float f32x4;
typedef __attribute__((ext_vector_type(4))) unsigned uint4v;
typedef __attribute__((ext_vector_type(2))) unsigned uint2v;

__device__ __forceinline__ unsigned bf16rne(float v) {
    unsigned u = __builtin_bit_cast(unsigned, v);
    return (u + 0x7fffu + ((u >> 16) & 1u)) >> 16;
}
__device__ __forceinline__ unsigned pack2(float a, float b) {
    return bf16rne(a) | (bf16rne(b) << 16);
}

// ---------------------------------------------------------------------------
// Prep: fold BN scale into pointwise weights (bf16) + fused bias.
// ---------------------------------------------------------------------------
__global__ __launch_bounds__(256) void prep_kernel(
    const float* __restrict__ pw_w, const float* __restrict__ pw_b,
    const float* __restrict__ pw_gamma, const float* __restrict__ pw_beta,
    const float* __restrict__ pw_mean, const float* __restrict__ pw_var,
    unsigned short* __restrict__ wb, float* __restrict__ bias2)
{
    const int idx = blockIdx.x * 256 + threadIdx.x;   // 0..32767
    const int o = idx >> 7;
    const float s = pw_gamma[o] * rsqrtf(pw_var[o] + BN_EPS);
    wb[idx] = (unsigned short)bf16rne(pw_w[idx] * s);
    if (idx < OO) {
        const float s2 = pw_gamma[idx] * rsqrtf(pw_var[idx] + BN_EPS);
        bias2[idx] = pw_b[idx] * s2 + pw_beta[idx] - pw_mean[idx] * s2;
    }
}

// ---------------------------------------------------------------------------
// Depthwise 3x3 + bias + BN + ReLU. Streaming: stores UNCUT bf16 y
// ([b][cg][hw][4c]) immediately per strip (low VGPR), accumulates per-channel
// plane max, then emits a 0xFFFF/0x0000 bf16-pair bitmask per (b,cg) that the
// pw kernel ANDs onto its A-fragments (the DW plane-cut).
// ---------------------------------------------------------------------------
__global__ __launch_bounds__(256) void dw_kernel(
    const float* __restrict__ x, const float* __restrict__ dw_w,
    const float* __restrict__ dw_b, const float* __restrict__ dw_gamma,
    const float* __restrict__ dw_beta, const float* __restrict__ dw_mean,
    const float* __restrict__ dw_var, unsigned short* __restrict__ y,
    uint2v* __restrict__ mask64)
{
    const int cg = blockIdx.x;       // 0..31
    const int b  = blockIdx.y;       // 0..31
    const int tid = threadIdx.x;
    const int c0 = cg * 4;

    float wk[4][9], sc[4], bi[4];
#pragma unroll
    for (int c = 0; c < 4; ++c) {
        const int ch = c0 + c;                    // block-uniform -> SGPRs
#pragma unroll
        for (int j = 0; j < 9; ++j) wk[c][j] = dw_w[ch * 9 + j];
        const float s = dw_gamma[ch] * rsqrtf(dw_var[ch] + BN_EPS);
        sc[c] = s;
        bi[c] = dw_b[ch] * s + dw_beta[ch] - dw_mean[ch] * s;
    }

    float cmax[4] = {0.f, 0.f, 0.f, 0.f};
    unsigned short* yp = y + ((size_t)(b * 32 + cg)) * HW4;

#pragma unroll
    for (int is = 0; is < 4; ++is) {
        const int s = tid + is * 256;
        if (s < 784) {
            const int r  = s / 14;
            const int m  = s - r * 14;
            const int q4 = m * 4;
            float vals[4][4];
#pragma unroll
            for (int c = 0; c < 4; ++c) {
                const float* px = x + ((size_t)(b * CC + c0 + c)) * HWSZ;
                float a0 = 0.f, a1 = 0.f, a2 = 0.f, a3 = 0.f;
#pragma unroll
                for (int dr = 0; dr < 3; ++dr) {
                    const int rr = r + dr - 1;
                    const bool vr2 = (rr >= 0) && (rr < 56);
                    const float* prow = px + rr * 56 + q4;
                    float4 M = vr2 ? *(const float4*)prow
                                   : make_float4(0.f, 0.f, 0.f, 0.f);
                    float xm = (vr2 && m > 0)  ? prow[-1] : 0.f;
                    float xp = (vr2 && m < 13) ? prow[4]  : 0.f;
                    const float w0 = wk[c][dr*3+0];
                    const float w1 = wk[c][dr*3+1];
                    const float w2 = wk[c][dr*3+2];
                    a0 += w0*xm  + w1*M.x + w2*M.y;
                    a1 += w0*M.x + w1*M.y + w2*M.z;
                    a2 += w0*M.y + w1*M.z + w2*M.w;
                    a3 += w0*M.z + w1*M.w + w2*xp;
                }
                float v0 = fmaxf(a0*sc[c]+bi[c], 0.f);
                float v1 = fmaxf(a1*sc[c]+bi[c], 0.f);
                float v2 = fmaxf(a2*sc[c]+bi[c], 0.f);
                float v3 = fmaxf(a3*sc[c]+bi[c], 0.f);
                vals[c][0] = v0; vals[c][1] = v1;
                vals[c][2] = v2; vals[c][3] = v3;
                cmax[c] = fmaxf(cmax[c], fmaxf(fmaxf(v0, v1), fmaxf(v2, v3)));
            }
            uint4 p0, p1;
            p0.x = pack2(vals[0][0], vals[1][0]);
            p0.y = pack2(vals[2][0], vals[3][0]);
            p0.z = pack2(vals[0][1], vals[1][1]);
            p0.w = pack2(vals[2][1], vals[3][1]);
            p1.x = pack2(vals[0][2], vals[1][2]);
            p1.y = pack2(vals[2][2], vals[3][2]);
            p1.z = pack2(vals[0][3], vals[1][3]);
            p1.w = pack2(vals[2][3], vals[3][3]);
            *(uint4*)(yp + (size_t)s * 16)     = p0;
            *(uint4*)(yp + (size_t)s * 16 + 8) = p1;
        }
    }

    // block-wide per-channel max
#pragma unroll
    for (int c = 0; c < 4; ++c)
#pragma unroll
        for (int off = 32; off; off >>= 1)
            cmax[c] = fmaxf(cmax[c], __shfl_xor(cmax[c], off, 64));
    __shared__ float smax[4][4];
    if ((tid & 63) == 0) {
#pragma unroll
        for (int c = 0; c < 4; ++c) smax[tid >> 6][c] = cmax[c];
    }
    __syncthreads();
    if (tid == 0) {
        unsigned mw[4];
#pragma unroll
        for (int c = 0; c < 4; ++c) {
            float mx = fmaxf(fmaxf(smax[0][c], smax[1][c]),
                             fmaxf(smax[2][c], smax[3][c]));
            mw[c] = (mx < DW_THR) ? 0u : 0xFFFFu;
        }
        uint2v mv;
        mv.x = mw[0] | (mw[1] << 16);
        mv.y = mw[2] | (mw[3] << 16);
        mask64[b * 32 + cg] = mv;
    }
}

// ---------------------------------------------------------------------------
// Pointwise 1x1 conv as bf16 MFMA GEMM, operands swapped (A=Y, B=W) so the
// accumulator holds 4 consecutive n per lane -> float4 stores.
// No LDS: A-frags read straight from global y (tile is L1-resident across the
// 4 waves); W frags + bias + cut-masks hoisted. PW cut skipped (< 1e-3).
// ---------------------------------------------------------------------------
__global__ __launch_bounds__(256) void pw_kernel(
    const unsigned short* __restrict__ yt,   // [b][32][3136][4] bf16 (uncut)
    const unsigned short* __restrict__ wb,   // [256][128] bf16 (BN-scaled)
    const float* __restrict__ bias2,         // [256]
    const uint2v* __restrict__ mask64,       // [b][32] channel-cut masks
    float* __restrict__ out)
{
    const int n0 = blockIdx.x * 64;
    const int b  = blockIdx.y;
    const int tid = threadIdx.x;
    const int ow  = (tid >> 6) * 64;         // wave o base
    const int l   = tid & 63;
    const int g   = l >> 4;                  // k-group 0..3
    const int lan = l & 15;

    const unsigned short* yb = yt + (size_t)b * (32 * HW4);

    // hoist cut masks: per kk, words for cg = kk*8+2g and kk*8+2g+1
    uint4v mk[4];
    const uint2v* mb = mask64 + b * 32;
#pragma unroll
    for (int kk = 0; kk < 4; ++kk)
        mk[kk] = *(const uint4v*)&mb[kk * 8 + 2 * g];

    float bv[4];
#pragma unroll
    for (int orr = 0; orr < 4; ++orr)
        bv[orr] = bias2[ow + orr * 16 + lan];

    f32x4 acc[4][4] = {};                    // [mr(n)][or(o)]

#pragma unroll
    for (int kk = 0; kk < 4; ++kk) {
        short8 bfr[4];
#pragma unroll
        for (int orr = 0; orr < 4; ++orr)
            bfr[orr] = *(const short8*)(wb
                + (size_t)(ow + orr * 16 + lan) * CC + kk * 32 + g * 8);
#pragma unroll
        for (int mr = 0; mr < 4; ++mr) {
            const unsigned short* ya = yb + (size_t)(kk * 8 + 2 * g) * HW4
                                       + (size_t)(n0 + mr * 16 + lan) * 4;
            uint2v lo = *(const uint2v*)ya;
            uint2v hi = *(const uint2v*)(ya + HW4);
            uint4v w4;
            w4.x = lo.x & mk[kk].x;
            w4.y = lo.y & mk[kk].y;
            w4.z = hi.x & mk[kk].z;
            w4.w = hi.y & mk[kk].w;
            const short8 a = __builtin_bit_cast(short8, w4);
#pragma unroll
            for (int orr = 0; orr < 4; ++orr)
                acc[mr][orr] = __builtin_amdgcn_mfma_f32_16x16x32_bf16(
                    a, bfr[orr], acc[mr][orr], 0, 0, 0);
        }
    }

    // epilogue: bias + relu, float4 stores (lane owns 4 consecutive n)
#pragma unroll
    for (int mr = 0; mr < 4; ++mr) {
#pragma unroll
        for (int orr = 0; orr < 4; ++orr) {
            const int o = ow + orr * 16 + lan;
            float4 r;
            r.x = fmaxf(acc[mr][orr][0] + bv[orr], 0.f);
            r.y = fmaxf(acc[mr][orr][1] + bv[orr], 0.f);
            r.z = fmaxf(acc[mr][orr][2] + bv[orr], 0.f);
            r.w = fmaxf(acc[mr][orr][3] + bv[orr], 0.f);
            *(float4*)&out[((size_t)b * OO + o) * HWSZ
                           + n0 + mr * 16 + g * 4] = r;
        }
    }
}

// ---------------------------------------------------------------------------
extern "C" void kernel_launch(void* const* d_in, const int* in_sizes, int n_in,
                              void* d_out, int out_size, void* d_ws, size_t ws_size,
                              hipStream_t stream)
{
    const float* x        = (const float*)d_in[0];
    const float* dw_w     = (const float*)d_in[1];
    const float* dw_b     = (const float*)d_in[2];
    const float* dw_gamma = (const float*)d_in[3];
    const float* dw_beta  = (const float*)d_in[4];
    const float* dw_mean  = (const float*)d_in[5];
    const float* dw_var   = (const float*)d_in[6];
    const float* pw_w     = (const float*)d_in[7];
    const float* pw_b     = (const float*)d_in[8];
    const float* pw_gamma = (const float*)d_in[9];
    const float* pw_beta  = (const float*)d_in[10];
    const float* pw_mean  = (const float*)d_in[11];
    const float* pw_var   = (const float*)d_in[12];

    // ws layout: y bf16 (25.69 MB) | Wb (64 KB) | bias2 (1 KB) | masks (8 KB)
    unsigned short* yws  = (unsigned short*)d_ws;
    unsigned short* wbuf = (unsigned short*)((char*)d_ws + 25690112);
    float*          b2   = (float*)((char*)d_ws + 25690112 + 65536);
    uint2v*         msk  = (uint2v*)((char*)d_ws + 25690112 + 65536 + 1024);

    prep_kernel<<<128, 256, 0, stream>>>(pw_w, pw_b, pw_gamma, pw_beta,
                                         pw_mean, pw_var, wbuf, b2);

    dim3 g1(32, 32);
    dw_kernel<<<g1, 256, 0, stream>>>(x, dw_w, dw_b, dw_gamma, dw_beta,
                                      dw_mean, dw_var, yws, msk);

    dim3 g2(49, 32);
    pw_kernel<<<g2, 256, 0, stream>>>(yws, wbuf, b2, msk, (float*)d_out);
}